// Round 6
// baseline (20721.948 us; speedup 1.0000x reference)
//
#include <hip/hip_runtime.h>
#include <math.h>

#define T_STEPS 4096
#define HDIM    2048
#define KDIM    2048
#define NG      8192      // 4*H
#define NREC    2048      // records per slot: one {h,tag} per h element
#define NSLOT   3         // 3-slot rotation (lap safety without counters)

typedef unsigned long long ull;

// ---------------- init ----------------
// recs[3][NREC]: tagged h records, 8B each: {lo: h bits, hi: tag}.
// Producer of step t writes tag t+1 into slot t%3; consumer at step t
// polls slot (t-1)%3 for tag t. Slot 2 = h0 (tag 0); slots 0,1 sentinel.
__global__ void init_ws5(const float* __restrict__ h0,
                         uint2* __restrict__ recs) {    // [NSLOT][NREC]
    int d = blockIdx.x * blockDim.x + threadIdx.x;
    if (d < NSLOT * NREC) {
        int slot = d >> 11;          // NREC = 2048
        int r = d & (NREC - 1);
        uint2 v;
        if (slot == 2) {
            v.x = __float_as_uint(h0[r]);
            v.y = 0u;                      // tag 0
        } else {
            v.x = 0u;
            v.y = 0xFFFFFFFFu;             // sentinel
        }
        recs[d] = v;
    }
}

// ---------------- Phase 1: Y = X @ Wi + bias ----------------
// ROUND 6: 128x128 tile, 8x8 accumulators/thread (was 64x64/4x4, ~85 TF).
// Doubled arithmetic intensity -> target ~130-150 TF of the 157 TF fp32
// vector ceiling.
__global__ __launch_bounds__(256) void gemm_xwi(
    const float* __restrict__ X, const float* __restrict__ Wi,
    const float* __restrict__ bias, float* __restrict__ Y)
{
    __shared__ float As[16][132];            // transposed A tile [k][m], +4 pad
    __shared__ __align__(16) float Bs[16][128];
    const int tid = threadIdx.x;
    const int m0 = blockIdx.y * 128;
    const int n0 = blockIdx.x * 128;
    const int tx = tid & 15;                 // n-frag = tx*8
    const int ty = tid >> 4;                 // m-frag = ty*8
    const int ar = tid >> 2, ak = (tid & 3) * 4;   // A: rows ar, ar+64
    const int bk = tid >> 5, bn = (tid & 31) * 4;  // B: rows bk, bk+8

    float acc[8][8];
#pragma unroll
    for (int i = 0; i < 8; ++i)
#pragma unroll
        for (int j = 0; j < 8; ++j) acc[i][j] = 0.f;

    for (int kt = 0; kt < KDIM; kt += 16) {
        float4 a0 = *reinterpret_cast<const float4*>(&X[(size_t)(m0 + ar) * KDIM + kt + ak]);
        float4 a1 = *reinterpret_cast<const float4*>(&X[(size_t)(m0 + ar + 64) * KDIM + kt + ak]);
        float4 b0 = *reinterpret_cast<const float4*>(&Wi[(size_t)(kt + bk) * NG + n0 + bn]);
        float4 b1 = *reinterpret_cast<const float4*>(&Wi[(size_t)(kt + bk + 8) * NG + n0 + bn]);
        __syncthreads();
        As[ak + 0][ar] = a0.x; As[ak + 1][ar] = a0.y;
        As[ak + 2][ar] = a0.z; As[ak + 3][ar] = a0.w;
        As[ak + 0][ar + 64] = a1.x; As[ak + 1][ar + 64] = a1.y;
        As[ak + 2][ar + 64] = a1.z; As[ak + 3][ar + 64] = a1.w;
        *reinterpret_cast<float4*>(&Bs[bk][bn])     = b0;
        *reinterpret_cast<float4*>(&Bs[bk + 8][bn]) = b1;
        __syncthreads();
#pragma unroll
        for (int k = 0; k < 16; ++k) {
            float4 aA = *reinterpret_cast<const float4*>(&As[k][ty * 8]);
            float4 aB = *reinterpret_cast<const float4*>(&As[k][ty * 8 + 4]);
            float4 bA = *reinterpret_cast<const float4*>(&Bs[k][tx * 8]);
            float4 bB = *reinterpret_cast<const float4*>(&Bs[k][tx * 8 + 4]);
            float am[8] = { aA.x, aA.y, aA.z, aA.w, aB.x, aB.y, aB.z, aB.w };
            float bv[8] = { bA.x, bA.y, bA.z, bA.w, bB.x, bB.y, bB.z, bB.w };
#pragma unroll
            for (int i = 0; i < 8; ++i)
#pragma unroll
                for (int j = 0; j < 8; ++j)
                    acc[i][j] = fmaf(am[i], bv[j], acc[i][j]);
        }
    }
    float4 bb0 = *reinterpret_cast<const float4*>(&bias[n0 + tx * 8]);
    float4 bb1 = *reinterpret_cast<const float4*>(&bias[n0 + tx * 8 + 4]);
#pragma unroll
    for (int i = 0; i < 8; ++i) {
        float4 o0, o1;
        o0.x = acc[i][0] + bb0.x; o0.y = acc[i][1] + bb0.y;
        o0.z = acc[i][2] + bb0.z; o0.w = acc[i][3] + bb0.w;
        o1.x = acc[i][4] + bb1.x; o1.y = acc[i][5] + bb1.y;
        o1.z = acc[i][6] + bb1.z; o1.w = acc[i][7] + bb1.w;
        float* yr = &Y[(size_t)(m0 + ty * 8 + i) * NG + n0 + tx * 8];
        *reinterpret_cast<float4*>(yr)     = o0;
        *reinterpret_cast<float4*>(yr + 4) = o1;
    }
}

// ---------------- fast activations ----------------
__device__ __forceinline__ float fsigm(float x) { return 1.f / (1.f + __expf(-x)); }
__device__ __forceinline__ float ftanh(float x) {
    float ax = fabsf(x);
    float e  = __expf(2.f * ax);
    float t  = (e - 1.f) / (e + 1.f);
    t = (ax > 15.f) ? 1.f : t;
    return copysignf(t, x);
}

// ---------------- Phase 2: persistent recurrent kernel ----------------
// 256 blocks x 512 threads, cooperative, 1 block/CU.
//
// ROUND 6 restructure: per-wave gate ownership. Wave w of block b owns
// h-element e = b*8+w and ALL FOUR of its gates (columns g*2048+e of Wh,
// g=0..3; per lane 32 rows x 4 cols = 128 weights, same count as before).
// Each wave reduces its 4 dot products in-wave, lane 0 applies the
// activations and publishes its record IMMEDIATELY -- in parallel with
// the other 7 waves. This removes the gates[] LDS round-trip, the 2nd
// __syncthreads, and the serial wave-0 epilogue of rounds 2-5. h staging
// is double-buffered (hbuf[t&1]) so the single remaining barrier per
// step is the staging->compute one; 2-step intra-block skew is blocked
// by that same barrier.
//
// Sync protocol (round-5, unchanged): fused detect+fetch tag-polling of
// self-validating 8B records {h, tag=t+1} stored with single
// global_store_dwordx2 sc0sc1 (single-copy atomic), 3-slot rotation.
// Lap-safety proof as round 5 (barrier aggregates per-thread tag checks;
// increment... i.e. publish-after-read is program order per thread).
__global__ __launch_bounds__(512)
__attribute__((amdgpu_waves_per_eu(2, 2)))
void lstm_persistent(
    const float* __restrict__ Y,     // [T][NG]
    const float* __restrict__ c0,
    const float* __restrict__ Wh,    // [K][NG]
    uint2* __restrict__ recs,        // [NSLOT][NREC] tagged h records
    float* __restrict__ out)         // [c_f][h_f][ys]
{
    const int b    = blockIdx.x;
    const int tid  = threadIdx.x;
    const int lane = tid & 63;
    const int w    = tid >> 6;       // 0..7 = owned h-element within block
    const int e    = b * 8 + w;      // global h index this wave owns

    __shared__ __align__(16) float hbuf[2][HDIM];   // 16 KiB double-buffered

    // ---- one-time weight load: 4 gate-columns x 32 rows per lane ----
    // wc[j][g] = Wh[(64*j + lane)][g*2048 + e]
    float wc[32][4];
#pragma unroll
    for (int j = 0; j < 32; ++j) {
        const float* wp = &Wh[(size_t)(64 * j + lane) * NG + e];
        wc[j][0] = wp[0];
        wc[j][1] = wp[2048];
        wc[j][2] = wp[4096];
        wc[j][3] = wp[6144];
        asm volatile("" : "+v"(wc[j][0]), "+v"(wc[j][1]),
                          "+v"(wc[j][2]), "+v"(wc[j][3]));
    }

    float c_r = c0[e];     // live on lane 0 (others unused)
    float h_r = 0.f;
    __syncthreads();

    int rs = 2;   // read slot for step t = (t-1) mod 3 ; t=0 -> 2
    int ws = 0;   // write slot for step t = t mod 3

    for (int t = 0; t < T_STEPS; ++t) {
        // Y prefetch: lane g (0-3) takes gate g's addend (hidden under poll)
        float yv = 0.f;
        if (lane < 4) yv = Y[(size_t)t * NG + (lane << 11) + e];

        // ---- fused detect+fetch: tag-poll own 2x16B (= 4 records) ----
        float* hb = hbuf[t & 1];
        {
            const uint2* rb = recs + (size_t)rs * NREC;
            const uint2* p0 = rb + 2 * tid;          // records 2tid, 2tid+1
            const uint2* p1 = rb + 1024 + 2 * tid;   // records 1024+2tid, +1
            const unsigned expt = (unsigned)t;
            uint4 ra, rc;   // {h_a, tag_a, h_b, tag_b}
            for (;;) {
                asm volatile("global_load_dwordx4 %0, %2, off sc0 sc1\n\t"
                             "global_load_dwordx4 %1, %3, off sc0 sc1\n\t"
                             "s_waitcnt vmcnt(0)"
                             : "=&v"(ra), "=&v"(rc)
                             : "v"(p0), "v"(p1) : "memory");
                if (__all((ra.y == expt) & (ra.w == expt) &
                          (rc.y == expt) & (rc.w == expt))) break;
                __builtin_amdgcn_s_sleep(1);
            }
            float2 d0; d0.x = __uint_as_float(ra.x); d0.y = __uint_as_float(ra.z);
            float2 d1; d1.x = __uint_as_float(rc.x); d1.y = __uint_as_float(rc.z);
            *reinterpret_cast<float2*>(&hb[2 * tid])        = d0;
            *reinterpret_cast<float2*>(&hb[1024 + 2 * tid]) = d1;
        }
        __syncthreads();   // staging complete (the ONLY barrier per step)

        // ---- 128 FMAs: 4 gate dot-products for element e ----
        float a0 = 0.f, a1 = 0.f, a2 = 0.f, a3 = 0.f;
#pragma unroll
        for (int j = 0; j < 32; ++j) {
            float hj = hb[64 * j + lane];     // stride-64: 2-way bank alias, free
            a0 = fmaf(hj, wc[j][0], a0);
            a1 = fmaf(hj, wc[j][1], a1);
            a2 = fmaf(hj, wc[j][2], a2);
            a3 = fmaf(hj, wc[j][3], a3);
        }
#pragma unroll
        for (int off = 32; off >= 1; off >>= 1) {
            a0 += __shfl_xor(a0, off);
            a1 += __shfl_xor(a1, off);
            a2 += __shfl_xor(a2, off);
            a3 += __shfl_xor(a3, off);
        }
        // lanes 0-3 hold full sums; add their gate's Y addend
        float sg = ((lane == 0) ? a0 : (lane == 1) ? a1
                  : (lane == 2) ? a2 : a3) + yv;
        float iv = __shfl(sg, 0);
        float fv = __shfl(sg, 1);
        float gv = __shfl(sg, 2);
        float ov = __shfl(sg, 3);

        // ---- per-wave epilogue: lane 0 activates + publishes, in
        //      parallel across the 8 waves, no second barrier ----
        if (lane == 0) {
            float cn = fsigm(fv) * c_r + fsigm(iv) * ftanh(gv);
            float hn = fsigm(ov) * ftanh(cn);
            c_r = cn;
            h_r = hn;
            ull rec = ((ull)(unsigned)(t + 1) << 32) | (ull)__float_as_uint(hn);
            uint2* dst = recs + (size_t)ws * NREC + e;
            asm volatile("global_store_dwordx2 %0, %1, off sc0 sc1"
                         :: "v"(dst), "v"(rec) : "memory");
            __builtin_nontemporal_store(hn, &out[2 * HDIM + (size_t)t * HDIM + e]);
        }

        rs = ws;
        ws = (ws == 2) ? 0 : ws + 1;
    }

    if (lane == 0) {
        out[e]        = c_r;   // c_f
        out[HDIM + e] = h_r;   // h_f
    }
}

// ---------------- launch ----------------
extern "C" void kernel_launch(void* const* d_in, const int* in_sizes, int n_in,
                              void* d_out, int out_size, void* d_ws, size_t ws_size,
                              hipStream_t stream) {
    const float* x   = (const float*)d_in[0];
    const float* c0  = (const float*)d_in[1];
    const float* h0  = (const float*)d_in[2];
    const float* Wi  = (const float*)d_in[3];
    const float* Wh  = (const float*)d_in[4];
    const float* bia = (const float*)d_in[5];
    float* out = (float*)d_out;

    char* base = (char*)d_ws;
    float* Y = (float*)base;                                  // 128 MiB
    base += (size_t)T_STEPS * NG * sizeof(float);
    uint2* recs = (uint2*)base;                               // 48 KiB

    const int initN = NSLOT * NREC;
    hipLaunchKernelGGL(init_ws5, dim3((initN + 511) / 512), dim3(512), 0, stream,
                       h0, recs);
    hipLaunchKernelGGL(gemm_xwi, dim3(NG / 128, T_STEPS / 128), dim3(256), 0, stream,
                       x, Wi, bia, Y);

    void* args[] = { (void*)&Y, (void*)&c0, (void*)&Wh,
                     (void*)&recs, (void*)&out };
    (void)hipLaunchCooperativeKernel((const void*)lstm_persistent, dim3(256), dim3(512),
                                     args, 0, stream);
}